// Round 5
// baseline (359.847 us; speedup 1.0000x reference)
//
#include <hip/hip_runtime.h>
#include <hip/hip_bf16.h>

// DCNv2 CrossNet on MI355X — fused 3-layer kernel, v9.
// Structural change vs v8: wave-PRIVATE weight staging rings. In this
// decomposition each wave only reads the B-fragments it stages itself
// (wave wc: V frags wc*2+nt, U frags wc*4+nt) -> no cross-wave barrier is
// needed around staging. Each wave owns a 3 KB LDS ring (3 x 1KB frag
// slots), staged via global_load_lds and synchronized with counted
// `s_waitcnt vmcnt(2)` (+ sched_barrier(0) fences, guide rule 18) — never
// vmcnt(0) inside the loop. v8's ~33 barriers/layer (each = vmcnt(0) drain
// with ONE resident block -> whole-CU idle) drop to 5/layer, and BT=32
// (LDS 81408 B) gives 2 blocks/CU so those 5 are hidden by the co-resident
// block. In-flight staging bytes: 16 waves x 2KB = 32KB/CU >= BW*latency
// (~22KB) -> L2-BW-bound. Gate GEMM replaced by a uniform VALU dot
// (gw staged bf16 in LDS) so no wave-0 divergence and no stray vmem inside
// the rings (ring vmcnt accounting must be exact; creg/bias loads are
// issued at layer start and drained at B1).
//
// Shapes: x[32768,512]; Vs[3,4,64,512]; Cs[3,4,64,64]; Us[3,4,512,64];
//         bias[3,512]; gate_w[512,4].

#define CROSS   3
#define ENUM    4
#define LR      64
#define ELD     256     // ENUM*LR
#define DIM     512
#define BATCH   32768
#define BT      32      // batch rows per block
#define NTHR    512     // 8 waves

#define XL_W    520     // 512 + 8 pad (shorts)
#define Y_W     264     // 256 + 8 pad (shorts)

typedef __bf16 bf16x8 __attribute__((ext_vector_type(8)));
typedef float  f32x4  __attribute__((ext_vector_type(4)));
typedef unsigned short us;
typedef unsigned short us4 __attribute__((ext_vector_type(4)));

__device__ __forceinline__ us f2bf(float f) {
    return __builtin_bit_cast(us, (__bf16)f);
}
__device__ __forceinline__ float bf2f(us b) {
    unsigned int u = ((unsigned int)b) << 16;
    return __builtin_bit_cast(float, u);
}
// fast tanh: (e^2x - 1) / (e^2x + 1); inputs bounded by 0.05-scaled weights.
__device__ __forceinline__ float tanh_fast(float x) {
    float t = __expf(2.f * x);
    return (t - 1.f) * __builtin_amdgcn_rcpf(t + 1.f);
}

#define MFMA(a, b, c) __builtin_amdgcn_mfma_f32_16x16x32_bf16(a, b, c, 0, 0, 0)

// async global->LDS copy, 16 B per lane. lds dest wave-uniform; HW writes
// lane l at dst + l*16. Global src is per-lane.
__device__ __forceinline__ void gload_lds16(const us* g, us* l) {
    __builtin_amdgcn_global_load_lds(
        (const __attribute__((address_space(1))) unsigned int*)g,
        (__attribute__((address_space(3))) unsigned int*)l, 16, 0, 0);
}

// counted wait on the staging ring: `left` = frags still to be issued after
// this one (min(2, last_f - f)). Constant-folds after full unroll.
__device__ __forceinline__ void wait_slot(int left) {
    if (left >= 2)      asm volatile("s_waitcnt vmcnt(2)" ::: "memory");
    else if (left == 1) asm volatile("s_waitcnt vmcnt(1)" ::: "memory");
    else                asm volatile("s_waitcnt vmcnt(0)" ::: "memory");
}

// ---------------------------------------------------------------------------
// Swizzle prepass: fp32 weights -> bf16 MFMA-B fragment order
// frag[nt][ks][lane][8]: n = nt*16 + (lane&15), k = ks*32 + (lane>>4)*8 + j.
// ---------------------------------------------------------------------------
__global__ __launch_bounds__(64) void swz_all(
    const float* __restrict__ Vs, const float* __restrict__ Cs,
    const float* __restrict__ Us,
    us* __restrict__ Vf, us* __restrict__ Cf, us* __restrict__ Uf)
{
    int b = blockIdx.x;
    int lane = threadIdx.x;
    if (b < 768) {                       // V: [3][16 nt][16 ks]
        int i = b >> 8, t = b & 255;
        int nt = t >> 4, ks = t & 15;
        int n  = nt * 16 + (lane & 15);
        int k0 = ks * 32 + (lane >> 4) * 8;
        const float* src = Vs + (size_t)i * ELD * DIM + (size_t)n * DIM + k0;
        us* dst = Vf + (size_t)i * ELD * DIM
                + ((size_t)(nt * 16 + ks) * 64 + lane) * 8;
        #pragma unroll
        for (int j = 0; j < 8; ++j) dst[j] = f2bf(src[j]);
    } else if (b < 1536) {               // U': [3][32 nt][8 ks], k = e*64+l
        int bb = b - 768;
        int i = bb >> 8, t = bb & 255;
        int nt = t >> 3, ks = t & 7;
        int n  = nt * 16 + (lane & 15);            // d
        int k0 = ks * 32 + (lane >> 4) * 8;        // e*64 + l
        int e = k0 >> 6, l0 = k0 & 63;
        const float* src = Us + (size_t)i * ENUM * DIM * LR
                         + (size_t)e * DIM * LR + (size_t)n * LR + l0;
        us* dst = Uf + (size_t)i * DIM * ELD
                + ((size_t)(nt * 8 + ks) * 64 + lane) * 8;
        #pragma unroll
        for (int j = 0; j < 8; ++j) dst[j] = f2bf(src[j]);
    } else {                             // C: [3][4 e][4 nt][2 ks]
        int bb = b - 1536;
        int i = bb >> 5, rest = bb & 31;
        int e = rest >> 3, t = rest & 7;
        int nt = t >> 1, ks = t & 1;
        int n  = nt * 16 + (lane & 15);
        int k0 = ks * 32 + (lane >> 4) * 8;
        const float* src = Cs + (((size_t)(i * ENUM + e) * LR + n) * LR) + k0;
        us* dst = Cf + (size_t)i * ENUM * LR * LR
                + ((size_t)((e * 4 + nt) * 2 + ks) * 64 + lane) * 8;
        #pragma unroll
        for (int j = 0; j < 8; ++j) dst[j] = f2bf(src[j]);
    }
}

// ---------------------------------------------------------------------------
// Fused 3-layer kernel. Block: 32 rows, 512 threads (8 waves), 2 blocks/CU.
// Thread element ownership (16x16x32 D-layout, mt in 0..1):
//   row = mt*16 + quad*4 + r,  col(G3) = wc*64 + nt*16 + nl.
// G1: wave wc owns Y cols [wc*32,+32) (nt_r=2); V frags wc*2+nt staged in
// the wave's private ring. Gate: uniform VALU dot, all 512 threads.
// G2: expert e = wc>>1, col-half h = wc&1; C frags in registers.
// G3: wave owns cols [wc*64,+64) (nt_r=4); U frags wc*4+nt via ring.
// Ring: 3 x 1KB slots/wave; issue frag f+3 after frag f's MFMAs; wait with
// counted vmcnt (2/1/0 near the tail). Barriers: 5/layer, rings never
// straddle a barrier (prologue issues land at the barrier's drain).
// ---------------------------------------------------------------------------
__global__ __launch_bounds__(NTHR, 4) void dcn_fused(
    const float* __restrict__ x,
    float* __restrict__ out,
    const us* __restrict__ Vf,
    const us* __restrict__ Cf,
    const us* __restrict__ Uf,
    const float* __restrict__ gw,
    const float* __restrict__ bias)
{
    __shared__ us xl_s[BT * XL_W];                   // 33280 B
    __shared__ us y_s[BT * Y_W];                     // 16896 B (Y then z)
    __shared__ us wst[8 * 1536];                     // 24576 B, 3KB/wave
    __shared__ us gw_s[4 * 512];                     // 4096 B, gate_w [e][d]
    __shared__ __align__(16) float g_s[BT * ENUM];   // 512 B
    __shared__ __align__(16) float sc[NTHR];         // 2048 B partials
    // total 81408 B -> 2 blocks/CU (162816 <= 163840)

    const int tid  = threadIdx.x;
    const int wave = tid >> 6, lane = tid & 63;
    const int quad = lane >> 4, nl = lane & 15;
    const int wc   = wave;
    const int row0 = blockIdx.x * BT;

#define ISSUE_V(f) gload_lds16( \
    Vl + ((size_t)((wc * 2 + ((f) & 1)) * 16 + ((f) >> 1)) * 64 + lane) * 8, \
    &wst[wave * 1536 + ((f) % 3) * 512])
#define ISSUE_U(f) gload_lds16( \
    Ul + ((size_t)((wc * 4 + ((f) & 3)) * 8 + ((f) >> 2)) * 64 + lane) * 8, \
    &wst[wave * 1536 + ((f) % 3) * 512])

    // ---- stage x -> xl_s (bf16): 32*128 = 4096 float4s, 8 per thread
    #pragma unroll
    for (int it = 0; it < 8; ++it) {
        int f4 = tid + it * NTHR;            // 0..4095
        int r = f4 >> 7, c4 = f4 & 127;
        float4 v = *reinterpret_cast<const float4*>(
            x + (size_t)(row0 + r) * DIM + c4 * 4);
        us4 p;
        p[0] = f2bf(v.x); p[1] = f2bf(v.y); p[2] = f2bf(v.z); p[3] = f2bf(v.w);
        *reinterpret_cast<us4*>(&xl_s[r * XL_W + c4 * 4]) = p;
    }
    // ---- stage gate_w -> gw_s[e][d] (bf16), 4 elems/thread
    #pragma unroll
    for (int j = 0; j < 4; ++j) {
        int idx = tid * 4 + j;               // 0..2047
        int e = idx >> 9, d = idx & 511;
        gw_s[idx] = f2bf(gw[(size_t)d * ENUM + e]);
    }
    __syncthreads();

    // ---- x0 packed bf16 in regs (thread's ownership elements)
    unsigned int x0p[2][4][2];
    #pragma unroll
    for (int mt = 0; mt < 2; ++mt)
        #pragma unroll
        for (int nt = 0; nt < 4; ++nt) {
            int rb = mt * 16 + quad * 4;
            int col = wc * 64 + nt * 16 + nl;
            unsigned int b0 = xl_s[(rb + 0) * XL_W + col];
            unsigned int b1 = xl_s[(rb + 1) * XL_W + col];
            unsigned int b2 = xl_s[(rb + 2) * XL_W + col];
            unsigned int b3 = xl_s[(rb + 3) * XL_W + col];
            x0p[mt][nt][0] = b0 | (b1 << 16);
            x0p[mt][nt][1] = b2 | (b3 << 16);
        }

    const int e = wc >> 1, h = wc & 1;       // GEMM2 roles

    #pragma unroll 1
    for (int layer = 0; layer < CROSS; ++layer) {
        const us* Vl = Vf + (size_t)layer * ELD * DIM;
        const us* Cl = Cf + (size_t)layer * ENUM * LR * LR;
        const us* Ul = Uf + (size_t)layer * DIM * ELD;
        const float* bl = bias + layer * DIM;

        // ---- layer-start register prefetches (drained at B1)
        bf16x8 creg[2][2];
        #pragma unroll
        for (int ks = 0; ks < 2; ++ks)
            #pragma unroll
            for (int nt = 0; nt < 2; ++nt)
                creg[ks][nt] = *reinterpret_cast<const bf16x8*>(
                    &Cl[((size_t)((e * 4 + h * 2 + nt) * 2 + ks) * 64 + lane) * 8]);
        float bias_r[4];
        #pragma unroll
        for (int nt = 0; nt < 4; ++nt)
            bias_r[nt] = bl[wc * 64 + nt * 16 + nl];

        // ---- V ring prologue (lands at B1's drain)
        ISSUE_V(0); ISSUE_V(1); ISSUE_V(2);
        __syncthreads();                     // B1: xl published + ring landed

        // ---- gate partials: thread (row, e, quarter) does 128 MACs.
        // dd rotated by quarter to spread LDS banks.
        {
            int grow = tid >> 4, ge = (tid >> 2) & 3, gq = tid & 3;
            float gp = 0.f;
            #pragma unroll
            for (int dd = 0; dd < 16; ++dd) {
                int d0 = gq * 128 + ((dd + gq * 4) & 15) * 8;
                bf16x8 xa = *reinterpret_cast<const bf16x8*>(
                    &xl_s[grow * XL_W + d0]);
                bf16x8 wa = *reinterpret_cast<const bf16x8*>(
                    &gw_s[ge * 512 + d0]);
                #pragma unroll
                for (int j = 0; j < 8; ++j)
                    gp += (float)xa[j] * (float)wa[j];
            }
            sc[tid] = gp;
        }
        __syncthreads();                     // B1b: partials published
        if (tid < 128)
            g_s[tid] = sc[tid * 4] + sc[tid * 4 + 1]
                     + sc[tid * 4 + 2] + sc[tid * 4 + 3];

        // ---- GEMM1: Y = tanh(xl @ V^T); wave-private ring, no barriers
        f32x4 acc1[2][2];
        acc1[0][0] = (f32x4)0.f; acc1[0][1] = (f32x4)0.f;
        acc1[1][0] = (f32x4)0.f; acc1[1][1] = (f32x4)0.f;
        #pragma unroll
        for (int ks = 0; ks < 16; ++ks) {
            bf16x8 a0 = *reinterpret_cast<const bf16x8*>(
                &xl_s[(nl) * XL_W + ks * 32 + quad * 8]);
            bf16x8 a1 = *reinterpret_cast<const bf16x8*>(
                &xl_s[(16 + nl) * XL_W + ks * 32 + quad * 8]);
            #pragma unroll
            for (int nt = 0; nt < 2; ++nt) {
                const int f = ks * 2 + nt;
                wait_slot(31 - f);
                __builtin_amdgcn_sched_barrier(0);
                bf16x8 b = *reinterpret_cast<const bf16x8*>(
                    &wst[wave * 1536 + (f % 3) * 512 + lane * 8]);
                acc1[0][nt] = MFMA(a0, b, acc1[0][nt]);
                acc1[1][nt] = MFMA(a1, b, acc1[1][nt]);
                __builtin_amdgcn_sched_barrier(0);
                if (f + 3 < 32) { ISSUE_V(f + 3); }
            }
        }
        // write Y
        #pragma unroll
        for (int mt = 0; mt < 2; ++mt)
            #pragma unroll
            for (int r = 0; r < 4; ++r) {
                int row = mt * 16 + quad * 4 + r;
                #pragma unroll
                for (int nt = 0; nt < 2; ++nt)
                    y_s[row * Y_W + wc * 32 + nt * 16 + nl] =
                        f2bf(tanh_fast(acc1[mt][nt][r]));
            }
        __syncthreads();                     // B2: Y + g ready

        // ---- Gv = sum_e g[row][e]
        float Gv[2][4];
        #pragma unroll
        for (int mt = 0; mt < 2; ++mt)
            #pragma unroll
            for (int r = 0; r < 4; ++r) {
                int row = mt * 16 + quad * 4 + r;
                f32x4 g4 = *reinterpret_cast<const f32x4*>(&g_s[row * ENUM]);
                Gv[mt][r] = g4[0] + g4[1] + g4[2] + g4[3];
            }

        // ---- U ring prologue (streams during G2, lands at B3's drain)
        ISSUE_U(0); ISSUE_U(1); ISSUE_U(2);

        // ---- GEMM2: z = g ⊙ tanh(Y_e @ C_e^T), C from registers
        f32x4 acc2[2][2];
        acc2[0][0] = (f32x4)0.f; acc2[0][1] = (f32x4)0.f;
        acc2[1][0] = (f32x4)0.f; acc2[1][1] = (f32x4)0.f;
        #pragma unroll
        for (int ks = 0; ks < 2; ++ks) {
            bf16x8 a0 = *reinterpret_cast<const bf16x8*>(
                &y_s[(nl) * Y_W + e * 64 + ks * 32 + quad * 8]);
            bf16x8 a1 = *reinterpret_cast<const bf16x8*>(
                &y_s[(16 + nl) * Y_W + e * 64 + ks * 32 + quad * 8]);
            #pragma unroll
            for (int nt = 0; nt < 2; ++nt) {
                acc2[0][nt] = MFMA(a0, creg[ks][nt], acc2[0][nt]);
                acc2[1][nt] = MFMA(a1, creg[ks][nt], acc2[1][nt]);
            }
        }
        __syncthreads();                     // B3: Y reads done, U0-2 landed
        #pragma unroll
        for (int mt = 0; mt < 2; ++mt)
            #pragma unroll
            for (int r = 0; r < 4; ++r) {
                int row = mt * 16 + quad * 4 + r;
                float gv = g_s[row * ENUM + e];
                #pragma unroll
                for (int nt = 0; nt < 2; ++nt)
                    y_s[row * Y_W + e * 64 + h * 32 + nt * 16 + nl] =
                        f2bf(tanh_fast(acc2[mt][nt][r]) * gv);
            }
        __syncthreads();                     // B4: z ready

        // ---- GEMM3: core = z @ U'^T, K=256; wave-private ring
        f32x4 acc3[2][4];
        #pragma unroll
        for (int mt = 0; mt < 2; ++mt)
            #pragma unroll
            for (int nt = 0; nt < 4; ++nt) acc3[mt][nt] = (f32x4)0.f;
        #pragma unroll
        for (int ks = 0; ks < 8; ++ks) {
            bf16x8 a0 = *reinterpret_cast<const bf16x8*>(
                &y_s[(nl) * Y_W + ks * 32 + quad * 8]);
            bf16x8 a1 = *reinterpret_cast<const bf16x8*>(
                &y_s[(16 + nl) * Y_W + ks * 32 + quad * 8]);
            #pragma unroll
            for (int nt = 0; nt < 4; ++nt) {
                const int f = ks * 4 + nt;
                wait_slot(31 - f);
                __builtin_amdgcn_sched_barrier(0);
                bf16x8 b = *reinterpret_cast<const bf16x8*>(
                    &wst[wave * 1536 + (f % 3) * 512 + lane * 8]);
                acc3[0][nt] = MFMA(a0, b, acc3[0][nt]);
                acc3[1][nt] = MFMA(a1, b, acc3[1][nt]);
                __builtin_amdgcn_sched_barrier(0);
                if (f + 3 < 32) { ISSUE_U(f + 3); }
            }
        }

        // ---- epilogue: xl = xl + x0 * (core + bias*G)
        #pragma unroll
        for (int nt = 0; nt < 4; ++nt) {
            int col = wc * 64 + nt * 16 + nl;
            #pragma unroll
            for (int mt = 0; mt < 2; ++mt)
                #pragma unroll
                for (int r = 0; r < 4; ++r) {
                    int row = mt * 16 + quad * 4 + r;
                    float x0v = bf2f(
                        (us)(x0p[mt][nt][r >> 1] >> ((r & 1) * 16)));
                    float xlo = bf2f(xl_s[row * XL_W + col]);
                    float res = xlo
                              + x0v * (acc3[mt][nt][r] + bias_r[nt] * Gv[mt][r]);
                    if (layer == CROSS - 1)
                        out[(size_t)(row0 + row) * DIM + col] = res;
                    else
                        xl_s[row * XL_W + col] = f2bf(res);
                }
        }
        // next layer's B1 publishes xl_s
    }
#undef ISSUE_V
#undef ISSUE_U
}

// ---------------------------------------------------------------------------
extern "C" void kernel_launch(void* const* d_in, const int* in_sizes, int n_in,
                              void* d_out, int out_size, void* d_ws,
                              size_t ws_size, hipStream_t stream) {
    const float* x      = (const float*)d_in[0];
    const float* Vs     = (const float*)d_in[1];
    const float* Cs     = (const float*)d_in[2];
    const float* Us     = (const float*)d_in[3];
    const float* bias   = (const float*)d_in[4];
    const float* gate_w = (const float*)d_in[5];
    float* out = (float*)d_out;

    us* Vf = (us*)d_ws;                                   // 393216 bf16
    us* Uf = Vf + (size_t)CROSS * ELD * DIM;              // 393216
    us* Cf = Uf + (size_t)CROSS * DIM * ELD;              // 49152

    swz_all<<<1632, 64, 0, stream>>>(Vs, Cs, Us, Vf, Cf, Uf);
    dcn_fused<<<BATCH / BT, NTHR, 0, stream>>>(x, out, Vf, Cf, Uf,
                                               gate_w, bias);
}

// Round 7
// 325.304 us; speedup vs baseline: 1.1062x; 1.1062x over previous
//
#include <hip/hip_runtime.h>
#include <hip/hip_bf16.h>

// DCNv2 CrossNet on MI355X — fused 3-layer kernel, v10b (compile fix of v10:
// nontemporal load via ext_vector_type pointer, not HIP float4 class).
// Synthesis of rounds 1-5:
//  * BT=64 / 16 waves / 1 block/CU, grid 512 = 2 clean rounds (v8's best
//    traffic point: FETCH 157 MB vs 297 at BT=32).
//  * Wave-PRIVATE staging rings (each wave global_load_lds's its OWN copy of
//    the B-frags it consumes -> per-wave vmcnt is exact; V/U L2-read dup is
//    ~25 B/cyc/CU, inside the L2 share). 3 slots, collision-free (issue f+2
//    -> slot (f+2)%3), steady wait vmcnt(1).
//  * Phase barriers DO NOT drain vmem: `s_waitcnt lgkmcnt(0); s_barrier`
//    only. v8's 33 draining barriers/layer (whole-CU idle each) drop to 5
//    non-draining ones; ring loads stay in flight across them.
//  * C-frag/bias vmem loads issued before the U-prologue so in-order vmcnt
//    retirement keeps G3's wait constants exact.
//  * x loads / out stores use __builtin_nontemporal_* so the 128 MB streams
//    stop evicting the 1.5 MB weight set from L2 (attacks v8's ~90 MB of
//    HBM weight refetch).
//  * Gate = uniform VALU dot (all 1024 threads), no divergent wave, no
//    stray vmem inside ring accounting.
//
// Shapes: x[32768,512]; Vs[3,4,64,512]; Cs[3,4,64,64]; Us[3,4,512,64];
//         bias[3,512]; gate_w[512,4].

#define CROSS   3
#define ENUM    4
#define LR      64
#define ELD     256     // ENUM*LR
#define DIM     512
#define BATCH   32768
#define BT      64      // batch rows per block
#define NTHR    1024    // 16 waves

#define XL_W    520     // 512 + 8 pad (shorts)
#define Y_W     264     // 256 + 8 pad (shorts)

typedef __bf16 bf16x8 __attribute__((ext_vector_type(8)));
typedef float  f32x4  __attribute__((ext_vector_type(4)));
typedef unsigned short us;
typedef unsigned short us4 __attribute__((ext_vector_type(4)));

__device__ __forceinline__ us f2bf(float f) {
    return __builtin_bit_cast(us, (__bf16)f);
}
__device__ __forceinline__ float bf2f(us b) {
    unsigned int u = ((unsigned int)b) << 16;
    return __builtin_bit_cast(float, u);
}
// fast tanh: (e^2x - 1) / (e^2x + 1); inputs bounded by 0.05-scaled weights.
__device__ __forceinline__ float tanh_fast(float x) {
    float t = __expf(2.f * x);
    return (t - 1.f) * __builtin_amdgcn_rcpf(t + 1.f);
}

#define MFMA(a, b, c) __builtin_amdgcn_mfma_f32_16x16x32_bf16(a, b, c, 0, 0, 0)

// async global->LDS copy, 16 B per lane. LDS dest wave-uniform; HW writes
// lane l at dst + l*16. Global src is per-lane.
__device__ __forceinline__ void gload_lds16(const us* g, us* l) {
    __builtin_amdgcn_global_load_lds(
        (const __attribute__((address_space(1))) unsigned int*)g,
        (__attribute__((address_space(3))) unsigned int*)l, 16, 0, 0);
}

#define WAITN(n)  asm volatile("s_waitcnt vmcnt(" #n ")" ::: "memory")
#define SBAR0()   __builtin_amdgcn_sched_barrier(0)
// Barrier that does NOT drain vmcnt: ds-visibility (lgkmcnt) + s_barrier.
#define LBAR() do { SBAR0(); \
    asm volatile("s_waitcnt lgkmcnt(0)" ::: "memory"); \
    __builtin_amdgcn_s_barrier(); SBAR0(); } while (0)

// ---------------------------------------------------------------------------
// Swizzle prepass: fp32 weights -> bf16 MFMA-B fragment order, vectorized.
// frag[nt][ks][lane][8]: n = nt*16 + (lane&15), k = ks*32 + (lane>>4)*8 + j.
// ---------------------------------------------------------------------------
__global__ __launch_bounds__(64) void swz_all(
    const float* __restrict__ Vs, const float* __restrict__ Cs,
    const float* __restrict__ Us,
    us* __restrict__ Vf, us* __restrict__ Cf, us* __restrict__ Uf)
{
    int b = blockIdx.x;
    int lane = threadIdx.x;
    const float* src;
    us* dst;
    if (b < 768) {                       // V: [3][16 nt][16 ks]
        int i = b >> 8, t = b & 255;
        int nt = t >> 4, ks = t & 15;
        int n  = nt * 16 + (lane & 15);
        int k0 = ks * 32 + (lane >> 4) * 8;
        src = Vs + (size_t)i * ELD * DIM + (size_t)n * DIM + k0;
        dst = Vf + (size_t)i * ELD * DIM
            + ((size_t)(nt * 16 + ks) * 64 + lane) * 8;
    } else if (b < 1536) {               // U': [3][32 nt][8 ks], k = e*64+l
        int bb = b - 768;
        int i = bb >> 8, t = bb & 255;
        int nt = t >> 3, ks = t & 7;
        int n  = nt * 16 + (lane & 15);            // d
        int k0 = ks * 32 + (lane >> 4) * 8;        // e*64 + l
        int e = k0 >> 6, l0 = k0 & 63;
        src = Us + (size_t)i * ENUM * DIM * LR
            + (size_t)e * DIM * LR + (size_t)n * LR + l0;
        dst = Uf + (size_t)i * DIM * ELD
            + ((size_t)(nt * 8 + ks) * 64 + lane) * 8;
    } else {                             // C: [3][4 e][4 nt][2 ks]
        int bb = b - 1536;
        int i = bb >> 5, rest = bb & 31;
        int e = rest >> 3, t = rest & 7;
        int nt = t >> 1, ks = t & 1;
        int n  = nt * 16 + (lane & 15);
        int k0 = ks * 32 + (lane >> 4) * 8;
        src = Cs + (((size_t)(i * ENUM + e) * LR + n) * LR) + k0;
        dst = Cf + (size_t)i * ENUM * LR * LR
            + ((size_t)((e * 4 + nt) * 2 + ks) * 64 + lane) * 8;
    }
    f32x4 s0 = *reinterpret_cast<const f32x4*>(src);
    f32x4 s1 = *reinterpret_cast<const f32x4*>(src + 4);
    us4 p0, p1;
    p0[0] = f2bf(s0[0]); p0[1] = f2bf(s0[1]); p0[2] = f2bf(s0[2]); p0[3] = f2bf(s0[3]);
    p1[0] = f2bf(s1[0]); p1[1] = f2bf(s1[1]); p1[2] = f2bf(s1[2]); p1[3] = f2bf(s1[3]);
    *reinterpret_cast<us4*>(dst)     = p0;
    *reinterpret_cast<us4*>(dst + 4) = p1;
}

// ---------------------------------------------------------------------------
// Fused 3-layer kernel. Block: 64 rows, 1024 threads (16 waves), 1 block/CU.
// Wave split: rh = wave>>3 (row half, 32 rows), wc = wave&7 (col group).
// Thread element ownership (16x16x32 D-layout, mt in 0..1):
//   row = rh*32 + mt*16 + quad*4 + r,  col(G3) = wc*64 + nt*16 + nl.
// G1: wc owns Y cols [wc*32,+32) (frags wc*2+nt). G2: e = wc>>1, h = wc&1,
// C from registers. G3: wc owns cols [wc*64,+64) (frags wc*4+nt).
// Ring: wave-private, 3 x 1KB slots; issue frag f+2 into slot (f+2)%3 while
// reading slot f%3 (never collides); steady wait vmcnt(1), tail vmcnt(0).
// Barriers (5/layer) are lgkm-only -> ring loads fly across them.
// ---------------------------------------------------------------------------
__global__ __launch_bounds__(NTHR, 4) void dcn_fused(
    const float* __restrict__ x,
    float* __restrict__ out,
    const us* __restrict__ Vf,
    const us* __restrict__ Cf,
    const us* __restrict__ Uf,
    const float* __restrict__ gw,
    const float* __restrict__ bias)
{
    __shared__ us xl_s[BT * XL_W];                   // 66560 B
    __shared__ us y_s[BT * Y_W];                     // 33792 B (Y then z)
    __shared__ us ring_s[16 * 3 * 512];              // 49152 B, 3KB/wave
    __shared__ us gw_s[4 * 512];                     // 4096 B, gate_w [e][d]
    __shared__ __align__(16) float g_s[BT * ENUM];   // 1024 B
    __shared__ __align__(16) float sc[NTHR];         // 4096 B partials
    // total 158720 B -> 1 block/CU, 16 waves (4/SIMD)

    const int tid  = threadIdx.x;
    const int wave = tid >> 6, lane = tid & 63;
    const int quad = lane >> 4, nl = lane & 15;
    const int rh = wave >> 3, wc = wave & 7;
    const int rh32 = rh * 32;
    const int row0 = blockIdx.x * BT;
    us* wring = &ring_s[wave * 1536];

#define ISSUE_V(f) gload_lds16( \
    Vl + ((size_t)((wc * 2 + ((f) & 1)) * 16 + ((f) >> 1)) * 64 + lane) * 8, \
    wring + ((f) % 3) * 512)
#define ISSUE_U(f) gload_lds16( \
    Ul + ((size_t)((wc * 4 + ((f) & 3)) * 8 + ((f) >> 2)) * 64 + lane) * 8, \
    wring + ((f) % 3) * 512)

    // ---- stage x -> xl_s (bf16): 64*128 = 8192 float4s, 8 per thread (nt)
    #pragma unroll
    for (int it = 0; it < 8; ++it) {
        int f4 = tid + it * NTHR;            // 0..8191
        int r = f4 >> 7, c4 = f4 & 127;
        f32x4 v = __builtin_nontemporal_load(
            reinterpret_cast<const f32x4*>(
                x + (size_t)(row0 + r) * DIM + c4 * 4));
        us4 p;
        p[0] = f2bf(v[0]); p[1] = f2bf(v[1]); p[2] = f2bf(v[2]); p[3] = f2bf(v[3]);
        *reinterpret_cast<us4*>(&xl_s[r * XL_W + c4 * 4]) = p;
    }
    // ---- stage gate_w -> gw_s[e][d] (bf16), 2 elems/thread
    #pragma unroll
    for (int j = 0; j < 2; ++j) {
        int idx = tid * 2 + j;               // 0..2047
        int e = idx >> 9, d = idx & 511;
        gw_s[idx] = f2bf(gw[(size_t)d * ENUM + e]);
    }
    LBAR();                                  // entry: xl_s + gw_s published

    // ---- x0 packed bf16 in regs (thread's ownership elements)
    unsigned int x0p[2][4][2];
    #pragma unroll
    for (int mt = 0; mt < 2; ++mt)
        #pragma unroll
        for (int nt = 0; nt < 4; ++nt) {
            int rb = rh32 + mt * 16 + quad * 4;
            int col = wc * 64 + nt * 16 + nl;
            unsigned int b0 = xl_s[(rb + 0) * XL_W + col];
            unsigned int b1 = xl_s[(rb + 1) * XL_W + col];
            unsigned int b2 = xl_s[(rb + 2) * XL_W + col];
            unsigned int b3 = xl_s[(rb + 3) * XL_W + col];
            x0p[mt][nt][0] = b0 | (b1 << 16);
            x0p[mt][nt][1] = b2 | (b3 << 16);
        }

    const int e = wc >> 1, h = wc & 1;       // GEMM2 roles

    #pragma unroll 1
    for (int layer = 0; layer < CROSS; ++layer) {
        const us* Vl = Vf + (size_t)layer * ELD * DIM;
        const us* Cl = Cf + (size_t)layer * ENUM * LR * LR;
        const us* Ul = Uf + (size_t)layer * DIM * ELD;
        const float* bl = bias + layer * DIM;

        // ---- V ring prologue (vmcnt clean here: prev phases fully drained)
        ISSUE_V(0); ISSUE_V(1);
        LBAR();                              // B1: xl_s published (no vm drain)

        // ---- gate partials: thread (row, e, quarter) does 128 MACs
        {
            int grow = tid >> 4, ge = (tid >> 2) & 3, gq = tid & 3;
            float gp = 0.f;
            #pragma unroll
            for (int dd = 0; dd < 16; ++dd) {
                int d0 = gq * 128 + ((dd + gq * 4) & 15) * 8;
                bf16x8 xa = *reinterpret_cast<const bf16x8*>(
                    &xl_s[grow * XL_W + d0]);
                bf16x8 wa = *reinterpret_cast<const bf16x8*>(
                    &gw_s[ge * 512 + d0]);
                #pragma unroll
                for (int j = 0; j < 8; ++j)
                    gp += (float)xa[j] * (float)wa[j];
            }
            sc[tid] = gp;
        }
        LBAR();                              // B1b: partials published
        if (tid < 256)
            g_s[tid] = sc[tid * 4] + sc[tid * 4 + 1]
                     + sc[tid * 4 + 2] + sc[tid * 4 + 3];

        // ---- GEMM1: Y = tanh(xl @ V^T); wave-private ring, no barriers
        f32x4 acc1[2][2];
        acc1[0][0] = (f32x4)0.f; acc1[0][1] = (f32x4)0.f;
        acc1[1][0] = (f32x4)0.f; acc1[1][1] = (f32x4)0.f;
        #pragma unroll
        for (int ks = 0; ks < 16; ++ks) {
            bf16x8 a0 = *reinterpret_cast<const bf16x8*>(
                &xl_s[(rh32 + nl) * XL_W + ks * 32 + quad * 8]);
            bf16x8 a1 = *reinterpret_cast<const bf16x8*>(
                &xl_s[(rh32 + 16 + nl) * XL_W + ks * 32 + quad * 8]);
            #pragma unroll
            for (int nt = 0; nt < 2; ++nt) {
                const int f = ks * 2 + nt;
                if (f < 31) { WAITN(1); } else { WAITN(0); }
                SBAR0();
                bf16x8 b = *reinterpret_cast<const bf16x8*>(
                    &wring[(f % 3) * 512 + lane * 8]);
                acc1[0][nt] = MFMA(a0, b, acc1[0][nt]);
                acc1[1][nt] = MFMA(a1, b, acc1[1][nt]);
                SBAR0();
                if (f + 2 < 32) { ISSUE_V(f + 2); }
            }
        }
        // ---- layer-constant vmem (positions 0..7 before U prologue 8,9)
        bf16x8 creg[2][2];
        #pragma unroll
        for (int ks = 0; ks < 2; ++ks)
            #pragma unroll
            for (int nt = 0; nt < 2; ++nt)
                creg[ks][nt] = *reinterpret_cast<const bf16x8*>(
                    &Cl[((size_t)((e * 4 + h * 2 + nt) * 2 + ks) * 64 + lane) * 8]);
        float bias_r[4];
        #pragma unroll
        for (int nt = 0; nt < 4; ++nt)
            bias_r[nt] = bl[wc * 64 + nt * 16 + nl];
        ISSUE_U(0); ISSUE_U(1);              // U ring prologue

        // write Y
        #pragma unroll
        for (int mt = 0; mt < 2; ++mt)
            #pragma unroll
            for (int r = 0; r < 4; ++r) {
                int row = rh32 + mt * 16 + quad * 4 + r;
                #pragma unroll
                for (int nt = 0; nt < 2; ++nt)
                    y_s[row * Y_W + wc * 32 + nt * 16 + nl] =
                        f2bf(tanh_fast(acc1[mt][nt][r]));
            }
        LBAR();                              // B2: Y + g ready (no vm drain)

        // ---- Gv = sum_e g[row][e]
        float Gv[2][4];
        #pragma unroll
        for (int mt = 0; mt < 2; ++mt)
            #pragma unroll
            for (int r = 0; r < 4; ++r) {
                int row = rh32 + mt * 16 + quad * 4 + r;
                f32x4 g4 = *reinterpret_cast<const f32x4*>(&g_s[row * ENUM]);
                Gv[mt][r] = g4[0] + g4[1] + g4[2] + g4[3];
            }

        // ---- GEMM2: z = g ⊙ tanh(Y_e @ C_e^T); compiler inserts the exact
        // vmcnt for creg (U prologue stays in flight).
        f32x4 acc2[2][2];
        acc2[0][0] = (f32x4)0.f; acc2[0][1] = (f32x4)0.f;
        acc2[1][0] = (f32x4)0.f; acc2[1][1] = (f32x4)0.f;
        #pragma unroll
        for (int ks = 0; ks < 2; ++ks) {
            bf16x8 a0 = *reinterpret_cast<const bf16x8*>(
                &y_s[(rh32 + nl) * Y_W + e * 64 + ks * 32 + quad * 8]);
            bf16x8 a1 = *reinterpret_cast<const bf16x8*>(
                &y_s[(rh32 + 16 + nl) * Y_W + e * 64 + ks * 32 + quad * 8]);
            #pragma unroll
            for (int nt = 0; nt < 2; ++nt) {
                acc2[0][nt] = MFMA(a0, creg[ks][nt], acc2[0][nt]);
                acc2[1][nt] = MFMA(a1, creg[ks][nt], acc2[1][nt]);
            }
        }
        LBAR();                              // B3: all Y reads done
        #pragma unroll
        for (int mt = 0; mt < 2; ++mt)
            #pragma unroll
            for (int r = 0; r < 4; ++r) {
                int row = rh32 + mt * 16 + quad * 4 + r;
                float gv = g_s[row * ENUM + e];
                #pragma unroll
                for (int nt = 0; nt < 2; ++nt)
                    y_s[row * Y_W + e * 64 + h * 32 + nt * 16 + nl] =
                        f2bf(tanh_fast(acc2[mt][nt][r]) * gv);
            }
        LBAR();                              // B4: z ready

        // ---- GEMM3: core = z @ U'^T, K=256; wave-private ring
        f32x4 acc3[2][4];
        #pragma unroll
        for (int mt = 0; mt < 2; ++mt)
            #pragma unroll
            for (int nt = 0; nt < 4; ++nt) acc3[mt][nt] = (f32x4)0.f;
        #pragma unroll
        for (int ks = 0; ks < 8; ++ks) {
            bf16x8 a0 = *reinterpret_cast<const bf16x8*>(
                &y_s[(rh32 + nl) * Y_W + ks * 32 + quad * 8]);
            bf16x8 a1 = *reinterpret_cast<const bf16x8*>(
                &y_s[(rh32 + 16 + nl) * Y_W + ks * 32 + quad * 8]);
            #pragma unroll
            for (int nt = 0; nt < 4; ++nt) {
                const int f = ks * 4 + nt;
                if (f < 31) { WAITN(1); } else { WAITN(0); }
                SBAR0();
                bf16x8 b = *reinterpret_cast<const bf16x8*>(
                    &wring[(f % 3) * 512 + lane * 8]);
                acc3[0][nt] = MFMA(a0, b, acc3[0][nt]);
                acc3[1][nt] = MFMA(a1, b, acc3[1][nt]);
                SBAR0();
                if (f + 2 < 32) { ISSUE_U(f + 2); }
            }
        }

        // ---- epilogue: xl = xl + x0 * (core + bias*G)
        #pragma unroll
        for (int nt = 0; nt < 4; ++nt) {
            int col = wc * 64 + nt * 16 + nl;
            #pragma unroll
            for (int mt = 0; mt < 2; ++mt)
                #pragma unroll
                for (int r = 0; r < 4; ++r) {
                    int row = rh32 + mt * 16 + quad * 4 + r;
                    float x0v = bf2f(
                        (us)(x0p[mt][nt][r >> 1] >> ((r & 1) * 16)));
                    float xlo = bf2f(xl_s[row * XL_W + col]);
                    float res = xlo
                              + x0v * (acc3[mt][nt][r] + bias_r[nt] * Gv[mt][r]);
                    if (layer == CROSS - 1)
                        __builtin_nontemporal_store(
                            res, &out[(size_t)(row0 + row) * DIM + col]);
                    else
                        xl_s[row * XL_W + col] = f2bf(res);
                }
        }
        // next layer's B1 publishes xl_s
    }
#undef ISSUE_V
#undef ISSUE_U
}

// ---------------------------------------------------------------------------
extern "C" void kernel_launch(void* const* d_in, const int* in_sizes, int n_in,
                              void* d_out, int out_size, void* d_ws,
                              size_t ws_size, hipStream_t stream) {
    const float* x      = (const float*)d_in[0];
    const float* Vs     = (const float*)d_in[1];
    const float* Cs     = (const float*)d_in[2];
    const float* Us     = (const float*)d_in[3];
    const float* bias   = (const float*)d_in[4];
    const float* gate_w = (const float*)d_in[5];
    float* out = (float*)d_out;

    us* Vf = (us*)d_ws;                                   // 393216 bf16
    us* Uf = Vf + (size_t)CROSS * ELD * DIM;              // 393216
    us* Cf = Uf + (size_t)CROSS * DIM * ELD;              // 49152

    swz_all<<<1632, 64, 0, stream>>>(Vs, Cs, Us, Vf, Cf, Uf);
    dcn_fused<<<BATCH / BT, NTHR, 0, stream>>>(x, out, Vf, Cf, Uf,
                                               gate_w, bias);
}

// Round 8
// 322.023 us; speedup vs baseline: 1.1175x; 1.0102x over previous
//
#include <hip/hip_runtime.h>
#include <hip/hip_bf16.h>

// DCNv2 CrossNet on MI355X — fused 3-layer kernel, v11.
// Fix of v10's diagnosed failure: wave-private rings DUPLICATED the V/U
// stream (rh-partner waves loaded identical frags) -> ~54 B/cyc/CU, at the
// ~56 B/cyc per-CU L2-port share -> queueing, FETCH 224 MB, 247 us.
// v11 stages each 16 KB K-slice ONCE per block (16 waves x 1 KB each via
// global_load_lds) and keeps v10's non-draining sync via a 3-slot /
// distance-2 / one-barrier-per-slice pipeline:
//   per slice k: s_waitcnt vmcnt(1)   (own slice-k load retired)
//                lgkm-only s_barrier  (rendezvous => slice k fully in LDS,
//                                      and reads of k-1 lgkm-drained)
//                issue slice k+2 -> slot (k+2)%3 = (k-1)%3 (provably free)
//                ds_read B-frags + 4 MFMA.
// vmcnt never drains to 0 except at phase tails. GEMM3 is re-sliced as
// (ks, nt-half) so its slices are also 16 KB and all 16 waves consume every
// slice. Weight stream/block: 1.57 MB -> ~12 us/block at the CU port.
// Other deltas vs v10: nt-store dropped (WRITE 142->188 regression), gate
// partial buffer aliased into y_s (LDS 154.6 KB, 1 block/CU, 16 waves).
//
// Shapes: x[32768,512]; Vs[3,4,64,512]; Cs[3,4,64,64]; Us[3,4,512,64];
//         bias[3,512]; gate_w[512,4].

#define CROSS   3
#define ENUM    4
#define LR      64
#define ELD     256     // ENUM*LR
#define DIM     512
#define BATCH   32768
#define BT      64      // batch rows per block
#define NTHR    1024    // 16 waves

#define XL_W    520     // 512 + 8 pad (shorts)
#define Y_W     264     // 256 + 8 pad (shorts)

typedef __bf16 bf16x8 __attribute__((ext_vector_type(8)));
typedef float  f32x4  __attribute__((ext_vector_type(4)));
typedef unsigned short us;
typedef unsigned short us4 __attribute__((ext_vector_type(4)));

__device__ __forceinline__ us f2bf(float f) {
    return __builtin_bit_cast(us, (__bf16)f);
}
__device__ __forceinline__ float bf2f(us b) {
    unsigned int u = ((unsigned int)b) << 16;
    return __builtin_bit_cast(float, u);
}
// fast tanh: (e^2x - 1) / (e^2x + 1); inputs bounded by 0.05-scaled weights.
__device__ __forceinline__ float tanh_fast(float x) {
    float t = __expf(2.f * x);
    return (t - 1.f) * __builtin_amdgcn_rcpf(t + 1.f);
}

#define MFMA(a, b, c) __builtin_amdgcn_mfma_f32_16x16x32_bf16(a, b, c, 0, 0, 0)

// async global->LDS copy, 16 B per lane. LDS dest wave-uniform; HW writes
// lane l at dst + l*16. Global src is per-lane.
__device__ __forceinline__ void gload_lds16(const us* g, us* l) {
    __builtin_amdgcn_global_load_lds(
        (const __attribute__((address_space(1))) unsigned int*)g,
        (__attribute__((address_space(3))) unsigned int*)l, 16, 0, 0);
}

#define WAITN(n)  asm volatile("s_waitcnt vmcnt(" #n ")" ::: "memory")
#define SBAR0()   __builtin_amdgcn_sched_barrier(0)
// Barrier that does NOT drain vmcnt: ds-visibility (lgkmcnt) + s_barrier.
#define LBAR() do { SBAR0(); \
    asm volatile("s_waitcnt lgkmcnt(0)" ::: "memory"); \
    __builtin_amdgcn_s_barrier(); SBAR0(); } while (0)

// ---------------------------------------------------------------------------
// Swizzle prepass: fp32 weights -> bf16 MFMA-B fragment order, vectorized.
// frag[nt][ks][lane][8]: n = nt*16 + (lane&15), k = ks*32 + (lane>>4)*8 + j.
// ---------------------------------------------------------------------------
__global__ __launch_bounds__(64) void swz_all(
    const float* __restrict__ Vs, const float* __restrict__ Cs,
    const float* __restrict__ Us,
    us* __restrict__ Vf, us* __restrict__ Cf, us* __restrict__ Uf)
{
    int b = blockIdx.x;
    int lane = threadIdx.x;
    const float* src;
    us* dst;
    if (b < 768) {                       // V: [3][16 nt][16 ks]
        int i = b >> 8, t = b & 255;
        int nt = t >> 4, ks = t & 15;
        int n  = nt * 16 + (lane & 15);
        int k0 = ks * 32 + (lane >> 4) * 8;
        src = Vs + (size_t)i * ELD * DIM + (size_t)n * DIM + k0;
        dst = Vf + (size_t)i * ELD * DIM
            + ((size_t)(nt * 16 + ks) * 64 + lane) * 8;
    } else if (b < 1536) {               // U': [3][32 nt][8 ks], k = e*64+l
        int bb = b - 768;
        int i = bb >> 8, t = bb & 255;
        int nt = t >> 3, ks = t & 7;
        int n  = nt * 16 + (lane & 15);            // d
        int k0 = ks * 32 + (lane >> 4) * 8;        // e*64 + l
        int e = k0 >> 6, l0 = k0 & 63;
        src = Us + (size_t)i * ENUM * DIM * LR
            + (size_t)e * DIM * LR + (size_t)n * LR + l0;
        dst = Uf + (size_t)i * DIM * ELD
            + ((size_t)(nt * 8 + ks) * 64 + lane) * 8;
    } else {                             // C: [3][4 e][4 nt][2 ks]
        int bb = b - 1536;
        int i = bb >> 5, rest = bb & 31;
        int e = rest >> 3, t = rest & 7;
        int nt = t >> 1, ks = t & 1;
        int n  = nt * 16 + (lane & 15);
        int k0 = ks * 32 + (lane >> 4) * 8;
        src = Cs + (((size_t)(i * ENUM + e) * LR + n) * LR) + k0;
        dst = Cf + (size_t)i * ENUM * LR * LR
            + ((size_t)((e * 4 + nt) * 2 + ks) * 64 + lane) * 8;
    }
    f32x4 s0 = *reinterpret_cast<const f32x4*>(src);
    f32x4 s1 = *reinterpret_cast<const f32x4*>(src + 4);
    us4 p0, p1;
    p0[0] = f2bf(s0[0]); p0[1] = f2bf(s0[1]); p0[2] = f2bf(s0[2]); p0[3] = f2bf(s0[3]);
    p1[0] = f2bf(s1[0]); p1[1] = f2bf(s1[1]); p1[2] = f2bf(s1[2]); p1[3] = f2bf(s1[3]);
    *reinterpret_cast<us4*>(dst)     = p0;
    *reinterpret_cast<us4*>(dst + 4) = p1;
}

// ---------------------------------------------------------------------------
// Fused 3-layer kernel. Block: 64 rows, 1024 threads (16 waves), 1 block/CU.
// Wave split: rh = wave>>3 (row half, 32 rows), wc = wave&7 (col group).
// Thread ownership (16x16x32 D-layout, mt in 0..1):
//   row = rh*32 + mt*16 + quad*4 + r,  col(G3) = wc*64 + nt*16 + nl.
// G1 slices: ks=0..15, slice = frags {nt*16+ks : nt 0..15} (16 KB); wave w
//   stages frag w*16+ks; consumer (rh,wc) reads offsets (wc*2+nt)*512.
// G3 slices: s=0..15, ks=s>>1, half=s&1; slice = frags
//   {(wc*4+half*2+j)*8+ks}; wave w stages frag ((w>>1)*4+half*2+(w&1))*8+ks;
//   consumer reads offsets (wc*2+j)*512, accumulates acc3[mt][half*2+j].
// Slice pipeline: 3 slots x 16 KB, issue distance 2, one lgkm-barrier per
// slice, steady wait vmcnt(1) (tail 0). All weight frags staged ONCE/block.
// ---------------------------------------------------------------------------
__global__ __launch_bounds__(NTHR, 4) void dcn_fused(
    const float* __restrict__ x,
    float* __restrict__ out,
    const us* __restrict__ Vf,
    const us* __restrict__ Cf,
    const us* __restrict__ Uf,
    const float* __restrict__ gw,
    const float* __restrict__ bias)
{
    __shared__ us xl_s[BT * XL_W];                   // 66560 B
    __shared__ __align__(16) us y_s[BT * Y_W];       // 33792 B (sc | Y | z)
    __shared__ us stg_s[3 * 8192];                   // 49152 B, 3 x 16KB slots
    __shared__ us gw_s[4 * 512];                     // 4096 B, gate_w [e][d]
    __shared__ __align__(16) float g_s[BT * ENUM];   // 1024 B
    // total 154624 B -> 1 block/CU, 16 waves (4/SIMD)
    float* sc = reinterpret_cast<float*>(y_s);       // gate partials alias

    const int tid  = threadIdx.x;
    const int wave = tid >> 6, lane = tid & 63;
    const int quad = lane >> 4, nl = lane & 15;
    const int rh = wave >> 3, wc = wave & 7;
    const int rh32 = rh * 32;
    const int row0 = blockIdx.x * BT;

#define ISSUE_V(k) gload_lds16( \
    Vl + ((size_t)(wave * 16 + (k)) * 64 + lane) * 8, \
    stg_s + ((k) % 3) * 8192 + wave * 512)
#define ISSUE_U(s) gload_lds16( \
    Ul + ((size_t)(((wave >> 1) * 4 + ((s) & 1) * 2 + (wave & 1)) * 8 \
                   + ((s) >> 1)) * 64 + lane) * 8, \
    stg_s + ((s) % 3) * 8192 + wave * 512)

    // ---- stage x -> xl_s (bf16): 64*128 = 8192 float4s, 8 per thread
    #pragma unroll
    for (int it = 0; it < 8; ++it) {
        int f4 = tid + it * NTHR;            // 0..8191
        int r = f4 >> 7, c4 = f4 & 127;
        f32x4 v = __builtin_nontemporal_load(
            reinterpret_cast<const f32x4*>(
                x + (size_t)(row0 + r) * DIM + c4 * 4));
        us4 p;
        p[0] = f2bf(v[0]); p[1] = f2bf(v[1]); p[2] = f2bf(v[2]); p[3] = f2bf(v[3]);
        *reinterpret_cast<us4*>(&xl_s[r * XL_W + c4 * 4]) = p;
    }
    // ---- stage gate_w -> gw_s[e][d] (bf16), 2 elems/thread
    #pragma unroll
    for (int j = 0; j < 2; ++j) {
        int idx = tid * 2 + j;               // 0..2047
        int e = idx >> 9, d = idx & 511;
        gw_s[idx] = f2bf(gw[(size_t)d * ENUM + e]);
    }
    LBAR();                                  // entry: xl_s + gw_s published

    // ---- x0 packed bf16 in regs (thread's ownership elements)
    unsigned int x0p[2][4][2];
    #pragma unroll
    for (int mt = 0; mt < 2; ++mt)
        #pragma unroll
        for (int nt = 0; nt < 4; ++nt) {
            int rb = rh32 + mt * 16 + quad * 4;
            int col = wc * 64 + nt * 16 + nl;
            unsigned int b0 = xl_s[(rb + 0) * XL_W + col];
            unsigned int b1 = xl_s[(rb + 1) * XL_W + col];
            unsigned int b2 = xl_s[(rb + 2) * XL_W + col];
            unsigned int b3 = xl_s[(rb + 3) * XL_W + col];
            x0p[mt][nt][0] = b0 | (b1 << 16);
            x0p[mt][nt][1] = b2 | (b3 << 16);
        }

    const int e = wc >> 1, h = wc & 1;       // GEMM2 roles

    #pragma unroll 1
    for (int layer = 0; layer < CROSS; ++layer) {
        const us* Vl = Vf + (size_t)layer * ELD * DIM;
        const us* Cl = Cf + (size_t)layer * ENUM * LR * LR;
        const us* Ul = Uf + (size_t)layer * DIM * ELD;
        const float* bl = bias + layer * DIM;

        // ---- layer-constant vmem (retired by slice-0's counted wait)
        bf16x8 creg[2][2];
        #pragma unroll
        for (int ks = 0; ks < 2; ++ks)
            #pragma unroll
            for (int nt = 0; nt < 2; ++nt)
                creg[ks][nt] = *reinterpret_cast<const bf16x8*>(
                    &Cl[((size_t)((e * 4 + h * 2 + nt) * 2 + ks) * 64 + lane) * 8]);
        float bias_r[4];
        #pragma unroll
        for (int nt = 0; nt < 4; ++nt)
            bias_r[nt] = bl[wc * 64 + nt * 16 + nl];

        ISSUE_V(0); ISSUE_V(1);              // slice prologue
        LBAR();                              // A: xl_s (prev epilogue) ready

        // ---- gate partials: thread (row, e, quarter) does 128 MACs
        {
            int grow = tid >> 4, ge = (tid >> 2) & 3, gq = tid & 3;
            float gp = 0.f;
            #pragma unroll
            for (int dd = 0; dd < 16; ++dd) {
                int d0 = gq * 128 + ((dd + gq * 4) & 15) * 8;
                bf16x8 xa = *reinterpret_cast<const bf16x8*>(
                    &xl_s[grow * XL_W + d0]);
                bf16x8 wa = *reinterpret_cast<const bf16x8*>(
                    &gw_s[ge * 512 + d0]);
                #pragma unroll
                for (int j = 0; j < 8; ++j)
                    gp += (float)xa[j] * (float)wa[j];
            }
            sc[tid] = gp;
        }
        LBAR();                              // B: partials published
        if (tid < 256)
            g_s[tid] = sc[tid * 4] + sc[tid * 4 + 1]
                     + sc[tid * 4 + 2] + sc[tid * 4 + 3];
        // (g_s published by slice-0's barrier below)

        // ---- GEMM1: Y = tanh(xl @ V^T); cooperative slices
        f32x4 acc1[2][2];
        acc1[0][0] = (f32x4)0.f; acc1[0][1] = (f32x4)0.f;
        acc1[1][0] = (f32x4)0.f; acc1[1][1] = (f32x4)0.f;
        #pragma unroll
        for (int ks = 0; ks < 16; ++ks) {
            if (ks < 15) { WAITN(1); } else { WAITN(0); }
            LBAR();                          // slice ks ready; slot free
            if (ks + 2 < 16) { ISSUE_V(ks + 2); }
            bf16x8 a0 = *reinterpret_cast<const bf16x8*>(
                &xl_s[(rh32 + nl) * XL_W + ks * 32 + quad * 8]);
            bf16x8 a1 = *reinterpret_cast<const bf16x8*>(
                &xl_s[(rh32 + 16 + nl) * XL_W + ks * 32 + quad * 8]);
            const us* sl = stg_s + (ks % 3) * 8192;
            #pragma unroll
            for (int nt = 0; nt < 2; ++nt) {
                bf16x8 b = *reinterpret_cast<const bf16x8*>(
                    &sl[(wc * 2 + nt) * 512 + lane * 8]);
                acc1[0][nt] = MFMA(a0, b, acc1[0][nt]);
                acc1[1][nt] = MFMA(a1, b, acc1[1][nt]);
            }
        }
        // write Y (overwrites sc region too — sc consumed above)
        #pragma unroll
        for (int mt = 0; mt < 2; ++mt)
            #pragma unroll
            for (int r = 0; r < 4; ++r) {
                int row = rh32 + mt * 16 + quad * 4 + r;
                #pragma unroll
                for (int nt = 0; nt < 2; ++nt)
                    y_s[row * Y_W + wc * 32 + nt * 16 + nl] =
                        f2bf(tanh_fast(acc1[mt][nt][r]));
            }
        ISSUE_U(0); ISSUE_U(1);              // U slice prologue
        LBAR();                              // C: Y published

        // ---- Gv = sum_e g[row][e]
        float Gv[2][4];
        #pragma unroll
        for (int mt = 0; mt < 2; ++mt)
            #pragma unroll
            for (int r = 0; r < 4; ++r) {
                int row = rh32 + mt * 16 + quad * 4 + r;
                f32x4 g4 = *reinterpret_cast<const f32x4*>(&g_s[row * ENUM]);
                Gv[mt][r] = g4[0] + g4[1] + g4[2] + g4[3];
            }

        // ---- GEMM2: z = g ⊙ tanh(Y_e @ C_e^T), C from registers
        f32x4 acc2[2][2];
        acc2[0][0] = (f32x4)0.f; acc2[0][1] = (f32x4)0.f;
        acc2[1][0] = (f32x4)0.f; acc2[1][1] = (f32x4)0.f;
        #pragma unroll
        for (int ks = 0; ks < 2; ++ks) {
            bf16x8 a0 = *reinterpret_cast<const bf16x8*>(
                &y_s[(rh32 + nl) * Y_W + e * 64 + ks * 32 + quad * 8]);
            bf16x8 a1 = *reinterpret_cast<const bf16x8*>(
                &y_s[(rh32 + 16 + nl) * Y_W + e * 64 + ks * 32 + quad * 8]);
            #pragma unroll
            for (int nt = 0; nt < 2; ++nt) {
                acc2[0][nt] = MFMA(a0, creg[ks][nt], acc2[0][nt]);
                acc2[1][nt] = MFMA(a1, creg[ks][nt], acc2[1][nt]);
            }
        }
        LBAR();                              // D: all Y reads done
        #pragma unroll
        for (int mt = 0; mt < 2; ++mt)
            #pragma unroll
            for (int r = 0; r < 4; ++r) {
                int row = rh32 + mt * 16 + quad * 4 + r;
                float gv = g_s[row * ENUM + e];
                #pragma unroll
                for (int nt = 0; nt < 2; ++nt)
                    y_s[row * Y_W + e * 64 + h * 32 + nt * 16 + nl] =
                        f2bf(tanh_fast(acc2[mt][nt][r]) * gv);
            }
        // (z published by GEMM3 slice-0's barrier)

        // ---- GEMM3: core = z @ U'^T; slices s=(ks,half)
        f32x4 acc3[2][4];
        #pragma unroll
        for (int mt = 0; mt < 2; ++mt)
            #pragma unroll
            for (int nt = 0; nt < 4; ++nt) acc3[mt][nt] = (f32x4)0.f;
        bf16x8 za0, za1;
        #pragma unroll
        for (int s = 0; s < 16; ++s) {
            if (s < 15) { WAITN(1); } else { WAITN(0); }
            LBAR();                          // slice s ready; slot free
            if (s + 2 < 16) { ISSUE_U(s + 2); }
            if ((s & 1) == 0) {
                int ks = s >> 1;
                za0 = *reinterpret_cast<const bf16x8*>(
                    &y_s[(rh32 + nl) * Y_W + ks * 32 + quad * 8]);
                za1 = *reinterpret_cast<const bf16x8*>(
                    &y_s[(rh32 + 16 + nl) * Y_W + ks * 32 + quad * 8]);
            }
            const us* sl = stg_s + (s % 3) * 8192;
            const int nb = (s & 1) * 2;
            #pragma unroll
            for (int j = 0; j < 2; ++j) {
                bf16x8 b = *reinterpret_cast<const bf16x8*>(
                    &sl[(wc * 2 + j) * 512 + lane * 8]);
                acc3[0][nb + j] = MFMA(za0, b, acc3[0][nb + j]);
                acc3[1][nb + j] = MFMA(za1, b, acc3[1][nb + j]);
            }
        }

        // ---- epilogue: xl = xl + x0 * (core + bias*G)
        #pragma unroll
        for (int nt = 0; nt < 4; ++nt) {
            int col = wc * 64 + nt * 16 + nl;
            #pragma unroll
            for (int mt = 0; mt < 2; ++mt)
                #pragma unroll
                for (int r = 0; r < 4; ++r) {
                    int row = rh32 + mt * 16 + quad * 4 + r;
                    float x0v = bf2f(
                        (us)(x0p[mt][nt][r >> 1] >> ((r & 1) * 16)));
                    float xlo = bf2f(xl_s[row * XL_W + col]);
                    float res = xlo
                              + x0v * (acc3[mt][nt][r] + bias_r[nt] * Gv[mt][r]);
                    if (layer == CROSS - 1)
                        out[(size_t)(row0 + row) * DIM + col] = res;
                    else
                        xl_s[row * XL_W + col] = f2bf(res);
                }
        }
        // next layer's barrier A publishes xl_s
    }
#undef ISSUE_V
#undef ISSUE_U
}

// ---------------------------------------------------------------------------
extern "C" void kernel_launch(void* const* d_in, const int* in_sizes, int n_in,
                              void* d_out, int out_size, void* d_ws,
                              size_t ws_size, hipStream_t stream) {
    const float* x      = (const float*)d_in[0];
    const float* Vs     = (const float*)d_in[1];
    const float* Cs     = (const float*)d_in[2];
    const float* Us     = (const float*)d_in[3];
    const float* bias   = (const float*)d_in[4];
    const float* gate_w = (const float*)d_in[5];
    float* out = (float*)d_out;

    us* Vf = (us*)d_ws;                                   // 393216 bf16
    us* Uf = Vf + (size_t)CROSS * ELD * DIM;              // 393216
    us* Cf = Uf + (size_t)CROSS * DIM * ELD;              // 49152

    swz_all<<<1632, 64, 0, stream>>>(Vs, Cs, Us, Vf, Cf, Uf);
    dcn_fused<<<BATCH / BT, NTHR, 0, stream>>>(x, out, Vf, Cf, Uf,
                                               gate_w, bias);
}